// Round 1
// baseline (293.155 us; speedup 1.0000x reference)
//
#include <hip/hip_runtime.h>

// GraphPooling: out[v] = mean over in-neighbors of h[src], else h[v] if deg==0.
// B=8, N=8192, F=64 -> 65536 nodes; E ~ 1M edges.
//
// Baseline: scatter-atomic into d_out (msum) + deg in d_ws, then finalize.

#define FDIM 64

__global__ void gp_scatter(const float* __restrict__ h,
                           const int* __restrict__ src,
                           const int* __restrict__ dst,
                           float* __restrict__ msum,
                           unsigned int* __restrict__ deg,
                           int E) {
    long long tid = (long long)blockIdx.x * blockDim.x + threadIdx.x;
    int edge = (int)(tid >> 6);
    int lane = (int)(tid & 63);
    if (edge >= E) return;
    int s = src[edge];
    int d = dst[edge];
    float v = h[(long long)s * FDIM + lane];
    atomicAdd(&msum[(long long)d * FDIM + lane], v);
    if (lane == 0) atomicAdd(&deg[d], 1u);
}

__global__ void gp_finalize(const float* __restrict__ h,
                            const unsigned int* __restrict__ deg,
                            float* __restrict__ out, int total) {
    int idx = blockIdx.x * blockDim.x + threadIdx.x;
    if (idx >= total) return;
    int v = idx >> 6;                 // node index (F=64)
    unsigned int d = deg[v];
    float ms = out[idx];
    out[idx] = (d > 0) ? ms / (float)d : h[idx];
}

extern "C" void kernel_launch(void* const* d_in, const int* in_sizes, int n_in,
                              void* d_out, int out_size, void* d_ws, size_t ws_size,
                              hipStream_t stream) {
    const float* h = (const float*)d_in[0];
    const int* src = (const int*)d_in[1];
    const int* dst = (const int*)d_in[2];
    float* out = (float*)d_out;
    int E = in_sizes[1];
    int total = out_size;             // 65536 * 64
    int nodes = total / FDIM;

    unsigned int* deg = (unsigned int*)d_ws;

    // Zero accumulators (d_out is poisoned; we own initialization).
    hipMemsetAsync(out, 0, (size_t)total * sizeof(float), stream);
    hipMemsetAsync(deg, 0, (size_t)nodes * sizeof(unsigned int), stream);

    // One wave (64 lanes) per edge.
    long long sthreads = (long long)E * 64;
    int sblocks = (int)((sthreads + 255) / 256);
    gp_scatter<<<sblocks, 256, 0, stream>>>(h, src, dst, out, deg, E);

    int fblocks = (total + 255) / 256;
    gp_finalize<<<fblocks, 256, 0, stream>>>(h, deg, out, total);
}

// Round 2
// 258.377 us; speedup vs baseline: 1.1346x; 1.1346x over previous
//
#include <hip/hip_runtime.h>

// GraphPooling: out[v] = mean over in-neighbors of h[src], else h[v] if deg==0.
// 65536 nodes x 64 f32 features, ~1M edges.
//
// CSR build (counting sort by dst) + segmented gather-mean.
// Avoids the 64M float atomics of the scatter baseline (295 MB atomic write
// traffic -> ~25 MB total writes).

#define FDIM 64
#define NODES 65536
#define SCAN_THREADS 1024
#define ELEMS_PER_THREAD 64   // 1024 * 64 = 65536

__global__ void gp_hist(const int* __restrict__ dst,
                        unsigned int* __restrict__ deg, int E) {
    int tid = blockIdx.x * blockDim.x + threadIdx.x;
    if (tid >= E) return;
    atomicAdd(&deg[dst[tid]], 1u);
}

// Single-block exclusive scan over NODES degrees -> offsets (and cursor copy).
__global__ void gp_scan(const unsigned int* __restrict__ deg,
                        unsigned int* __restrict__ offsets,
                        unsigned int* __restrict__ cursor) {
    __shared__ unsigned int part[SCAN_THREADS];
    int t = threadIdx.x;
    int base = t * ELEMS_PER_THREAD;

    // Local sum of this thread's 64 elements (vectorized as uint4).
    const uint4* d4 = (const uint4*)(deg + base);
    unsigned int lsum = 0;
    unsigned int vals[ELEMS_PER_THREAD];
    #pragma unroll
    for (int i = 0; i < ELEMS_PER_THREAD / 4; ++i) {
        uint4 v = d4[i];
        vals[i * 4 + 0] = v.x; vals[i * 4 + 1] = v.y;
        vals[i * 4 + 2] = v.z; vals[i * 4 + 3] = v.w;
        lsum += v.x + v.y + v.z + v.w;
    }
    part[t] = lsum;
    __syncthreads();

    // Hillis-Steele inclusive scan over 1024 partials.
    #pragma unroll
    for (int off = 1; off < SCAN_THREADS; off <<= 1) {
        unsigned int add = (t >= off) ? part[t - off] : 0u;
        __syncthreads();
        part[t] += add;
        __syncthreads();
    }
    unsigned int run = (t > 0) ? part[t - 1] : 0u;   // exclusive block prefix

    #pragma unroll
    for (int i = 0; i < ELEMS_PER_THREAD; ++i) {
        offsets[base + i] = run;
        cursor[base + i]  = run;
        run += vals[i];
    }
}

__global__ void gp_scatter_csr(const int* __restrict__ src,
                               const int* __restrict__ dst,
                               unsigned int* __restrict__ cursor,
                               int* __restrict__ ssrc, int E) {
    int tid = blockIdx.x * blockDim.x + threadIdx.x;
    if (tid >= E) return;
    int d = dst[tid];
    unsigned int pos = atomicAdd(&cursor[d], 1u);
    ssrc[pos] = src[tid];
}

// One wave (64 lanes) per node: lane f sums h[src*64+f] over the segment.
__global__ void gp_gather_mean(const float* __restrict__ h,
                               const int* __restrict__ ssrc,
                               const unsigned int* __restrict__ offsets,
                               const unsigned int* __restrict__ deg,
                               float* __restrict__ out, int nodes) {
    int gtid = blockIdx.x * blockDim.x + threadIdx.x;
    int v = gtid >> 6;        // wave id = node
    int lane = gtid & 63;
    if (v >= nodes) return;

    unsigned int start = offsets[v];
    unsigned int dg = deg[v];

    float acc = 0.0f;
    for (unsigned int j = 0; j < dg; ++j) {
        int s = ssrc[start + j];
        acc += h[(long long)s * FDIM + lane];
    }
    long long oidx = (long long)v * FDIM + lane;
    out[oidx] = (dg > 0) ? acc / (float)dg : h[oidx];
}

extern "C" void kernel_launch(void* const* d_in, const int* in_sizes, int n_in,
                              void* d_out, int out_size, void* d_ws, size_t ws_size,
                              hipStream_t stream) {
    const float* h = (const float*)d_in[0];
    const int* src = (const int*)d_in[1];
    const int* dst = (const int*)d_in[2];
    float* out = (float*)d_out;
    int E = in_sizes[1];
    int nodes = out_size / FDIM;     // 65536

    // Workspace layout.
    unsigned int* deg     = (unsigned int*)d_ws;                    // 256 KB
    unsigned int* offsets = deg + NODES;                            // 256 KB
    unsigned int* cursor  = offsets + NODES;                        // 256 KB
    int* ssrc             = (int*)(cursor + NODES);                 // 4 MB

    hipMemsetAsync(deg, 0, (size_t)nodes * sizeof(unsigned int), stream);

    int eblocks = (E + 255) / 256;
    gp_hist<<<eblocks, 256, 0, stream>>>(dst, deg, E);
    gp_scan<<<1, SCAN_THREADS, 0, stream>>>(deg, offsets, cursor);
    gp_scatter_csr<<<eblocks, 256, 0, stream>>>(src, dst, cursor, ssrc, E);

    long long gthreads = (long long)nodes * 64;
    int gblocks = (int)((gthreads + 255) / 256);
    gp_gather_mean<<<gblocks, 256, 0, stream>>>(h, ssrc, offsets, deg, out, nodes);
}

// Round 4
// 107.437 us; speedup vs baseline: 2.7286x; 2.4049x over previous
//
#include <hip/hip_runtime.h>

// GraphPooling: out[v] = mean over in-neighbors of h[src], else h[v] if deg==0.
// 65536 nodes x 64 f32 features, E = 1,048,576 edges.
//
// Pipeline: hist+rank (1M u32 atomics) -> 2-level scan -> atomic-free scatter
// (counting sort by dst, u16 payload) -> wave-per-node gather-mean with
// 4-edge-parallel float4 gathers.
//
// R3 bug fixed: inner gather loop now has WAVE-UNIFORM trip count so __shfl
// never reads from an inactive lane (per-lane bounds made egrp 2/3 exit early
// -> undefined bpermute reads -> absmax 0.385).

#define FDIM 64

__global__ void gp_hist_rank(const int* __restrict__ dst,
                             unsigned int* __restrict__ deg,
                             unsigned short* __restrict__ rank, int E) {
    int tid = blockIdx.x * blockDim.x + threadIdx.x;
    if (tid >= E) return;
    unsigned int r = atomicAdd(&deg[dst[tid]], 1u);
    rank[tid] = (unsigned short)r;
}

// 64 blocks x 1024 threads, 1 elem/thread: block-local exclusive scan + totals.
__global__ void gp_scan_local(const unsigned int* __restrict__ deg,
                              unsigned int* __restrict__ loc,
                              unsigned int* __restrict__ bsums) {
    int t = threadIdx.x;
    int g = blockIdx.x * 1024 + t;
    int lane = t & 63, wid = t >> 6;
    int v = (int)deg[g];
    int x = v;
    #pragma unroll
    for (int off = 1; off < 64; off <<= 1) {
        int y = __shfl_up(x, off);
        if (lane >= off) x += y;
    }
    __shared__ int wsum[16];
    if (lane == 63) wsum[wid] = x;
    __syncthreads();
    // 16-element scan of wave sums on a FULL wave (no divergent shfl).
    if (wid == 0) {
        int w = (lane < 16) ? wsum[lane] : 0;
        #pragma unroll
        for (int off = 1; off < 16; off <<= 1) {
            int y = __shfl_up(w, off);
            if (lane >= off) w += y;
        }
        if (lane < 16) wsum[lane] = w;
    }
    __syncthreads();
    int wpre = wid ? wsum[wid - 1] : 0;
    loc[g] = (unsigned int)(wpre + x - v);          // exclusive within block
    if (t == 1023) bsums[blockIdx.x] = (unsigned int)(wpre + x);
}

// 1 wave: exclusive scan of the 64 block totals.
__global__ void gp_scan_bsums(const unsigned int* __restrict__ bsums,
                              unsigned int* __restrict__ bofs) {
    int t = threadIdx.x;
    int v = (int)bsums[t];
    int x = v;
    #pragma unroll
    for (int off = 1; off < 64; off <<= 1) {
        int y = __shfl_up(x, off);
        if (t >= off) x += y;
    }
    bofs[t] = (unsigned int)(x - v);
}

// Atomic-free counting-sort scatter: pos = offset(dst) + rank.
__global__ void gp_scatter2(const int* __restrict__ src,
                            const int* __restrict__ dst,
                            const unsigned short* __restrict__ rank,
                            const unsigned int* __restrict__ loc,
                            const unsigned int* __restrict__ bofs,
                            unsigned short* __restrict__ ssrc, int E) {
    int tid = blockIdx.x * blockDim.x + threadIdx.x;
    if (tid >= E) return;
    int d = dst[tid];
    unsigned int pos = loc[d] + bofs[d >> 10] + (unsigned int)rank[tid];
    ssrc[pos] = (unsigned short)src[tid];
}

// One wave per node. lane = (egrp:2bits)(fq:4bits): egrp picks one of 4
// parallel edges, fq picks a float4 of the 64 features. Segment indices are
// loaded cooperatively (1 coalesced load per 64 edges), broadcast via shfl
// with a WAVE-UNIFORM loop bound (chunk is uniform: whole wave shares v).
__global__ void gp_gather2(const float* __restrict__ h,
                           const unsigned short* __restrict__ ssrc,
                           const unsigned int* __restrict__ loc,
                           const unsigned int* __restrict__ bofs,
                           const unsigned int* __restrict__ deg,
                           float* __restrict__ out, int nodes) {
    int gtid = blockIdx.x * blockDim.x + threadIdx.x;
    int v = gtid >> 6;
    int lane = gtid & 63;
    if (v >= nodes) return;   // never splits a wave: nodes*64 == grid threads

    unsigned int start = loc[v] + bofs[v >> 10];
    unsigned int dg = deg[v];
    int egrp = lane >> 4;
    int fq = lane & 15;
    const float4* h4 = (const float4*)h;

    float4 acc = make_float4(0.f, 0.f, 0.f, 0.f);
    for (unsigned int base = 0; base < dg; base += 64) {
        int chunk = (int)min(64u, dg - base);           // wave-uniform
        int sidx = (lane < chunk) ? (int)ssrc[start + base + lane] : 0;
        int nit = (chunk + 3) >> 2;                     // wave-uniform
        for (int it = 0; it < nit; ++it) {
            int j = it * 4 + egrp;
            int s = __shfl(sidx, (j < chunk) ? j : 0);  // all 64 lanes active
            float4 m = h4[(size_t)s * 16 + fq];
            if (j < chunk) {
                acc.x += m.x; acc.y += m.y; acc.z += m.z; acc.w += m.w;
            }
        }
    }
    // Butterfly-reduce the 4 edge groups (xor 16, 32) -> all lanes hold sum.
    #pragma unroll
    for (int k = 16; k <= 32; k <<= 1) {
        acc.x += __shfl_xor(acc.x, k);
        acc.y += __shfl_xor(acc.y, k);
        acc.z += __shfl_xor(acc.z, k);
        acc.w += __shfl_xor(acc.w, k);
    }
    if (lane < 16) {
        size_t oi = (size_t)v * 16 + fq;
        float4 r;
        if (dg > 0) {
            float inv = 1.0f / (float)dg;
            r = make_float4(acc.x * inv, acc.y * inv, acc.z * inv, acc.w * inv);
        } else {
            r = h4[oi];
        }
        ((float4*)out)[oi] = r;
    }
}

extern "C" void kernel_launch(void* const* d_in, const int* in_sizes, int n_in,
                              void* d_out, int out_size, void* d_ws, size_t ws_size,
                              hipStream_t stream) {
    const float* h = (const float*)d_in[0];
    const int* src = (const int*)d_in[1];
    const int* dst = (const int*)d_in[2];
    float* out = (float*)d_out;
    int E = in_sizes[1];
    int nodes = out_size / FDIM;     // 65536

    // Workspace layout (~4.5 MB).
    unsigned int* deg   = (unsigned int*)d_ws;            // 256 KB
    unsigned int* loc   = deg + 65536;                    // 256 KB
    unsigned int* bsums = loc + 65536;                    // 256 B
    unsigned int* bofs  = bsums + 64;                     // 256 B
    unsigned short* rank = (unsigned short*)(bofs + 64);  // 2 MB
    unsigned short* ssrc = rank + (size_t)E;              // 2 MB

    hipMemsetAsync(deg, 0, (size_t)nodes * sizeof(unsigned int), stream);

    int eblocks = (E + 255) / 256;
    gp_hist_rank<<<eblocks, 256, 0, stream>>>(dst, deg, rank, E);
    gp_scan_local<<<64, 1024, 0, stream>>>(deg, loc, bsums);
    gp_scan_bsums<<<1, 64, 0, stream>>>(bsums, bofs);
    gp_scatter2<<<eblocks, 256, 0, stream>>>(src, dst, rank, loc, bofs, ssrc, E);

    long long gthreads = (long long)nodes * 64;
    int gblocks = (int)((gthreads + 255) / 256);
    gp_gather2<<<gblocks, 256, 0, stream>>>(h, ssrc, loc, bofs, deg, out, nodes);
}